// Round 18
// baseline (134.772 us; speedup 1.0000x reference)
//
#include <hip/hip_runtime.h>

using u16 = unsigned short;
using u32 = unsigned int;
typedef __attribute__((ext_vector_type(8))) short bf16x8;
typedef __attribute__((ext_vector_type(4))) float f32x4;

__device__ __forceinline__ float bf2f(u32 h) {
  union { u32 u; float f; } c; c.u = h << 16; return c.f;
}
__device__ __forceinline__ u16 f2bf(float f) {
  union { float f; u32 u; } c; c.f = f;
  u32 u = c.u;
  u32 r = (u + 0x7FFFu + ((u >> 16) & 1u)) >> 16;
  return (u16)r;
}

#define GLD16(gsrc, ldst)                                                      \
  __builtin_amdgcn_global_load_lds(                                            \
      (const __attribute__((address_space(1))) unsigned int*)(gsrc),           \
      (__attribute__((address_space(3))) unsigned int*)(ldst), 16, 0, 0)

// kappa: virtual key order inside a 64-key tile so PV's A-frag is the natural
// register layout of the swapped QK^T output.
__device__ __forceinline__ int kappa(int ss) {
  return (ss & 0x23) | ((ss & 0x10) >> 2) | ((ss & 0x0C) << 1);
}

// one-hot bf16x8 A-frag word builder: hot halfword c in [0,8), zero otherwise
__device__ __forceinline__ bf16x8 onehot8(int c) {
  union { u32 w[4]; bf16x8 v; } u;
  u32 hv = (c & 1) ? 0x3F800000u : 0x3F80u;
#pragma unroll
  for (int k = 0; k < 4; ++k) u.w[k] = ((c >> 1) == k) ? hv : 0u;
  return u.v;
}

// ---------------------------------------------------------------- prep
__global__ void prep_kernel(const float* __restrict__ x, const float* __restrict__ qw,
                            const float* __restrict__ pw, const float* __restrict__ rph,
                            const float* __restrict__ rpw, u16* __restrict__ xb,
                            u16* __restrict__ qwb, u16* __restrict__ pwb,
                            u16* __restrict__ tbl) {
  int i = blockIdx.x * 256 + threadIdx.x;   // 2,164,736 total quads
  const float* src;
  u16* dst;
  int j;
  if (i < 1572864) { src = x; dst = xb; j = i; }
  else if (i < 2015232) { src = qw; dst = qwb; j = i - 1572864; }
  else if (i < 2162688) { src = pw; dst = pwb; j = i - 2015232; }
  else {
    int b = (i - 2162688) * 4;
    ushort4 o;
#pragma unroll
    for (int k = 0; k < 4; ++k) {
      int idx = b + k, row = idx >> 6, d = idx & 63;
      float v = 0.f;
      if (row < 63) v = rph[row * 64 + d];
      else if (row >= 64 && row < 127) v = rpw[(row - 64) * 64 + d];
      ((u16*)&o)[k] = f2bf(v * 8.0f);
    }
    *(ushort4*)&tbl[b] = o;
    return;
  }
  float4 v = *(const float4*)(src + j * 4);
  ushort4 o;
  o.x = f2bf(v.x); o.y = f2bf(v.y); o.z = f2bf(v.z); o.w = f2bf(v.w);
  *(ushort4*)(dst + j * 4) = o;
}

// ---------------------------------------------------------------- P gemm
__global__ __launch_bounds__(256, 2) void pgemm_kernel(
    const u16* __restrict__ A, const u16* __restrict__ tbl, u16* __restrict__ Q2) {
  __shared__ u16 Bs[128 * 64];
  const int tid = threadIdx.x;
  const int lane = tid & 63, wave = tid >> 6;
  const int lr = lane & 15, lg = lane >> 4;
  const int m0 = blockIdx.x * 256;
  const int wm = (wave >> 1) * 64, wn = (wave & 1) * 64;

#pragma unroll
  for (int i = 0; i < 4; ++i) {
    int c = tid + i * 256;
    int row = c >> 3, pp = c & 7;
    int pl = pp ^ (row & 7);  // pre-swizzled source, linear LDS dest
    GLD16(tbl + row * 64 + pl * 8, &Bs[c * 8]);
  }
  __syncthreads();

  bf16x8 b[4][2];
#pragma unroll
  for (int n = 0; n < 4; ++n) {
    int row = wn + n * 16 + lr;
#pragma unroll
    for (int kf = 0; kf < 2; ++kf)
      b[n][kf] = *(const bf16x8*)&Bs[(row * 64 + kf * 32 + lg * 8) ^ ((row & 7) << 3)];
  }

#pragma unroll
  for (int tt = 0; tt < 2; ++tt) {
    bf16x8 a[4][2];
#pragma unroll
    for (int m = 0; m < 4; ++m) {
      int g = m0 + tt * 128 + wm + m * 16 + lr;
#pragma unroll
      for (int kf = 0; kf < 2; ++kf)
        a[m][kf] = *(const bf16x8*)(A + (size_t)g * 128 + kf * 32 + lg * 8);
    }
    f32x4 acc[4][4] = {};
#pragma unroll
    for (int kf = 0; kf < 2; ++kf)
#pragma unroll
      for (int m = 0; m < 4; ++m)
#pragma unroll
        for (int n = 0; n < 4; ++n)
          acc[m][n] = __builtin_amdgcn_mfma_f32_16x16x32_bf16(a[m][kf], b[n][kf], acc[m][n], 0, 0, 0);

#pragma unroll
    for (int m = 0; m < 4; ++m)
#pragma unroll
      for (int n = 0; n < 4; ++n) {
        const int col = wn + n * 16 + lr;
#pragma unroll
        for (int r = 0; r < 4; ++r) {
          const int g = m0 + tt * 128 + wm + m * 16 + lg * 4 + r;
          const int s = g & 1023;
          const int hq = s >> 5, w = s & 31;
          u16 hv = f2bf(acc[m][n][r]);
          if (col < 64) {
            int kh = hq + 31 - col;
            if ((unsigned)kh < 32u) Q2[(size_t)g * 128 + 96 + kh] = hv;
          } else {
            int kw = w + 95 - col;
            if ((unsigned)kw < 32u) Q2[(size_t)g * 128 + 64 + kw] = hv;
          }
        }
      }
  }
}

// ---------------------------------------------------------------- 256x256 8-phase GEMM (QKV)
// T3+T4 schedule (HK/m201 template, plain HIP): BK=64, 8 waves (2M x 4N),
// wave tile = 2 m-strips x 2 n-strips of 64x32 quadrants. LDS 128 KB:
// 2 slots x {A[2 halves 128x64], B[2 halves 128x64]}, 8-chunk XOR swizzle.
// Half-tile stream h = phase+6, parts [A0,A1,B0,B1]; per phase: ds_read
// quadrant frags || stage 1 half-tile -> barrier -> 16 MFMA (setprio) ->
// vmcnt(4) at local phases 3,7 only -> barrier. Never drains vmcnt to 0
// mid-loop; every LDS overwrite targets a half whose reads ended in an
// earlier phase (two same-phase overlaps protected by issue order + >=180cy
// global latency). Accumulation order per element identical to 2-phase ver.
template <int MODE>
__global__ __launch_bounds__(512, 2) void gemm256(
    const u16* __restrict__ A, const u16* __restrict__ B,
    const float* __restrict__ bias, u16* __restrict__ oq, u16* __restrict__ ok,
    u16* __restrict__ ovt, float* __restrict__ ofp) {
  __shared__ u16 As[2][16384];   // [slot][half*8192 + row*64 + col]
  __shared__ u16 Bs[2][16384];
  const int tid = threadIdx.x;
  const int lane = tid & 63, wave = tid >> 6;
  const int lr = lane & 15, lg = lane >> 4;

  const int nbx = (MODE == 0) ? 9 : 3;
  const int nwg = nbx * 32;
  int id = blockIdx.y * nbx + blockIdx.x;
  int nid = (id & 7) * (nwg >> 3) + (id >> 3);
  const int m0 = (nid / nbx) * 256, n0 = (nid % nbx) * 256;
  const int wm64 = (wave >> 2) * 64, wn32 = (wave & 3) * 32;

  f32x4 acc[8][4] = {};   // [mh*4+m][nh*2+n]

  // fragment LDS offsets (within a 128x64 half)
  int aoff[4][2], boff[2][2];
#pragma unroll
  for (int m = 0; m < 4; ++m) {
    int row = wm64 + m * 16 + lr;
#pragma unroll
    for (int kf = 0; kf < 2; ++kf)
      aoff[m][kf] = (row * 64 + kf * 32 + lg * 8) ^ ((row & 7) << 3);
  }
#pragma unroll
  for (int n = 0; n < 2; ++n) {
    int row = wn32 + n * 16 + lr;
#pragma unroll
    for (int kf = 0; kf < 2; ++kf)
      boff[n][kf] = (row * 64 + kf * 32 + lg * 8) ^ ((row & 7) << 3);
  }

  // staging pointers: per half, 2 chunks/thread (1024 chunks = 128 rows x 8)
  const u16* pA[2][2];
  const u16* pB[2][2];
#pragma unroll
  for (int h = 0; h < 2; ++h)
#pragma unroll
    for (int i2 = 0; i2 < 2; ++i2) {
      int c = tid + i2 * 512;
      int row = c >> 3, pp = c & 7;
      int pl = pp ^ (row & 7);       // pre-swizzled global source, linear LDS dest
      if constexpr (MODE == 0) {
        pA[h][i2] = A + (size_t)(m0 + h * 128 + row) * 768 + pl * 8;
      } else {
        int g = m0 + h * 128 + row;
        pA[h][i2] = A + ((size_t)((g >> 10) * 12) << 16) + (g & 1023) * 64 + pl * 8;
      }
      pB[h][i2] = B + (size_t)(n0 + h * 128 + row) * 768 + pl * 8;
    }
  constexpr int dA = (MODE == 0) ? 64 : 65536;

  auto stageA = [&](int half, int slot) {
    GLD16(pA[half][0], &As[slot][half * 8192 + tid * 8]);
    GLD16(pA[half][1], &As[slot][half * 8192 + (tid + 512) * 8]);
    pA[half][0] += dA;
    pA[half][1] += dA;
  };
  auto stageB = [&](int half, int slot) {
    GLD16(pB[half][0], &Bs[slot][half * 8192 + tid * 8]);
    GLD16(pB[half][1], &Bs[slot][half * 8192 + (tid + 512) * 8]);
    pB[half][0] += 64;
    pB[half][1] += 64;
  };

  // prologue: t0 complete (slot0) + t1 A-halves (slot1); wait t0 (4 loads fly)
  stageA(0, 0); stageA(1, 0); stageB(0, 0); stageB(1, 0);
  stageA(0, 1); stageA(1, 1);
  asm volatile("s_waitcnt vmcnt(4)" ::: "memory");
  __builtin_amdgcn_sched_barrier(0);
  __builtin_amdgcn_s_barrier();
  __builtin_amdgcn_sched_barrier(0);

  bf16x8 a[4][2], b0[2][2], b1[2][2];

#pragma unroll 1
  for (int i = 0; i < 6; ++i) {
#pragma unroll
    for (int j = 0; j < 8; ++j) {
      const int tc = j >> 2;        // computed tile t = 2i+tc, slot = tc
      const int q = j & 3;
      const int mh = q >> 1, nh = q & 1;

      // ds_read this quadrant's fresh fragments
      if (q == 0) {
#pragma unroll
        for (int m = 0; m < 4; ++m)
#pragma unroll
          for (int kf = 0; kf < 2; ++kf)
            a[m][kf] = *(const bf16x8*)&As[tc][aoff[m][kf]];
#pragma unroll
        for (int n = 0; n < 2; ++n)
#pragma unroll
          for (int kf = 0; kf < 2; ++kf)
            b0[n][kf] = *(const bf16x8*)&Bs[tc][boff[n][kf]];
      } else if (q == 1) {
#pragma unroll
        for (int n = 0; n < 2; ++n)
#pragma unroll
          for (int kf = 0; kf < 2; ++kf)
            b1[n][kf] = *(const bf16x8*)&Bs[tc][8192 + boff[n][kf]];
      } else if (q == 2) {
#pragma unroll
        for (int m = 0; m < 4; ++m)
#pragma unroll
          for (int kf = 0; kf < 2; ++kf)
            a[m][kf] = *(const bf16x8*)&As[tc][8192 + aoff[m][kf]];
      }

      // stage one half-tile (h = p+6 stream): j0,1 -> t2i+1 B-halves (slot1);
      // j2..5 -> t2i+2 (slot0); j6,7 -> t2i+3 A-halves (slot1)
      if (j == 0) stageB(0, 1);
      else if (j == 1) stageB(1, 1);
      else if (i < 5) {
        if (j == 2) stageA(0, 0);
        else if (j == 3) stageA(1, 0);
        else if (j == 4) stageB(0, 0);
        else if (j == 5) stageB(1, 0);
        else if (j == 6) stageA(0, 1);
        else stageA(1, 1);
      }

      __builtin_amdgcn_sched_barrier(0);
      __builtin_amdgcn_s_barrier();
      __builtin_amdgcn_sched_barrier(0);

      __builtin_amdgcn_s_setprio(1);
#pragma unroll
      for (int kf = 0; kf < 2; ++kf)
#pragma unroll
        for (int m = 0; m < 4; ++m)
#pragma unroll
          for (int n = 0; n < 2; ++n)
            acc[mh * 4 + m][nh * 2 + n] = __builtin_amdgcn_mfma_f32_16x16x32_bf16(
                a[m][kf], (nh ? b1 : b0)[n][kf], acc[mh * 4 + m][nh * 2 + n], 0, 0, 0);
      __builtin_amdgcn_s_setprio(0);
      __builtin_amdgcn_sched_barrier(0);

      if (j == 3) {
        if (i < 5) asm volatile("s_waitcnt vmcnt(4)" ::: "memory");
        else asm volatile("s_waitcnt vmcnt(0)" ::: "memory");
      } else if (j == 7 && i < 5) {
        asm volatile("s_waitcnt vmcnt(4)" ::: "memory");
      }
      __builtin_amdgcn_s_barrier();
      __builtin_amdgcn_sched_barrier(0);
    }
  }

  // epilogue
#pragma unroll
  for (int mh = 0; mh < 2; ++mh)
#pragma unroll
    for (int m = 0; m < 4; ++m) {
      const int grow0 = m0 + mh * 128 + wm64 + m * 16 + lg * 4;
#pragma unroll
      for (int nh = 0; nh < 2; ++nh)
#pragma unroll
        for (int n = 0; n < 2; ++n) {
          const int gcol = n0 + nh * 128 + wn32 + n * 16 + lr;
          const float bv = bias[gcol];
          f32x4 av = acc[mh * 4 + m][nh * 2 + n];
          if constexpr (MODE == 0) {
            int which = (gcol >= 1536) ? 2 : (gcol >= 768 ? 1 : 0);
            int rem = gcol - which * 768;
            int bh = (grow0 >> 10) * 12 + (rem >> 6);
            if (which == 2) {
              int s0 = grow0 & 1023;
              int colb = (s0 & ~63) | kappa(s0 & 63);
              ushort4 pk;
              pk.x = f2bf(av[0] + bv);
              pk.y = f2bf(av[1] + bv);
              pk.z = f2bf(av[2] + bv);
              pk.w = f2bf(av[3] + bv);
              *(ushort4*)&ovt[((size_t)bh << 16) + (size_t)(rem & 63) * 1024 + colb] = pk;
            } else if (which == 0) {
#pragma unroll
              for (int r = 0; r < 4; ++r) {
                int s = (grow0 & 1023) + r;
                oq[((size_t)bh << 17) + s * 128 + (rem & 63)] =
                    f2bf((av[r] + bv) * 0.18033688f);
              }
            } else {
#pragma unroll
              for (int r = 0; r < 4; ++r) {
                int s = (grow0 & 1023) + r;
                ok[((size_t)bh << 16) + s * 64 + (rem & 63)] = f2bf(av[r] + bv);
              }
            }
          } else {
#pragma unroll
            for (int r = 0; r < 4; ++r)
              ofp[(size_t)(grow0 + r) * 768 + gcol] = av[r] + bv;
          }
        }
    }
}

// ---------------------------------------------------------------- GEMM (proj, proven)
// 128x128 tile, BK=64, 512 threads / 8 waves (wave tile 64x32).
template <int MODE>
__global__ __launch_bounds__(512, 2) void gemm128(
    const u16* __restrict__ A, const u16* __restrict__ B,
    const float* __restrict__ bias, u16* __restrict__ oq, u16* __restrict__ ok,
    u16* __restrict__ ovt, float* __restrict__ ofp) {
  __shared__ u16 As[2][128 * 64];
  __shared__ u16 Bs[2][128 * 64];
  const int tid = threadIdx.x;
  const int lane = tid & 63, wave = tid >> 6;
  const int lr = lane & 15, lg = lane >> 4;

  const int nbx = (MODE == 0) ? 18 : 6;
  const int nwg = nbx * 64;
  int id = blockIdx.y * nbx + blockIdx.x;
  int nid = (id & 7) * (nwg >> 3) + (id >> 3);
  const int m0 = (nid / nbx) * 128, n0 = (nid % nbx) * 128;
  const int wm = (wave >> 2) * 64, wn = (wave & 3) * 32;

  f32x4 acc[4][2] = {};

  int aoff[4][2], boff[2][2];
#pragma unroll
  for (int m = 0; m < 4; ++m) {
    int row = wm + m * 16 + lr;
#pragma unroll
    for (int kf = 0; kf < 2; ++kf)
      aoff[m][kf] = (row * 64 + kf * 32 + lg * 8) ^ ((row & 7) << 3);
  }
#pragma unroll
  for (int n = 0; n < 2; ++n) {
    int row = wn + n * 16 + lr;
#pragma unroll
    for (int kf = 0; kf < 2; ++kf)
      boff[n][kf] = (row * 64 + kf * 32 + lg * 8) ^ ((row & 7) << 3);
  }

  const u16* ap[2];
  const u16* bp[2];
#pragma unroll
  for (int i = 0; i < 2; ++i) {
    int c = tid + i * 512;
    int row = c >> 3, pp = c & 7;
    int pl = pp ^ (row & 7);
    if constexpr (MODE == 0) {
      ap[i] = A + (size_t)(m0 + row) * 768 + pl * 8;
    } else {
      int g = m0 + row;
      ap[i] = A + ((size_t)((g >> 10) * 12) << 16) + (g & 1023) * 64 + pl * 8;
    }
    bp[i] = B + (size_t)(n0 + row) * 768 + pl * 8;
  }
  constexpr int dA = (MODE == 0) ? 64 : 65536;

  auto stage = [&](int bi) {
#pragma unroll
    for (int i = 0; i < 2; ++i) {
      int c = tid + i * 512;
      GLD16(ap[i], &As[bi][c * 8]);
      GLD16(bp[i], &Bs[bi][c * 8]);
      ap[i] += dA;
      bp[i] += 64;
    }
  };

  stage(0);
#pragma unroll 1
  for (int t = 0; t < 12; ++t) {
    const int cur = t & 1;
    if (t < 11) {
      stage(cur ^ 1);
      asm volatile("s_waitcnt vmcnt(4)" ::: "memory");
    } else {
      asm volatile("s_waitcnt vmcnt(0)" ::: "memory");
    }
    __builtin_amdgcn_sched_barrier(0);
    __builtin_amdgcn_s_barrier();
    __builtin_amdgcn_sched_barrier(0);

    bf16x8 a[4][2], b[2][2];
#pragma unroll
    for (int m = 0; m < 4; ++m)
#pragma unroll
      for (int kf = 0; kf < 2; ++kf)
        a[m][kf] = *(const bf16x8*)&As[cur][aoff[m][kf]];
#pragma unroll
    for (int n = 0; n < 2; ++n)
#pragma unroll
      for (int kf = 0; kf < 2; ++kf)
        b[n][kf] = *(const bf16x8*)&Bs[cur][boff[n][kf]];
    __builtin_amdgcn_s_setprio(1);
#pragma unroll
    for (int kf = 0; kf < 2; ++kf)
#pragma unroll
      for (int m = 0; m < 4; ++m)
#pragma unroll
        for (int n = 0; n < 2; ++n)
          acc[m][n] = __builtin_amdgcn_mfma_f32_16x16x32_bf16(a[m][kf], b[n][kf], acc[m][n], 0, 0, 0);
    __builtin_amdgcn_s_setprio(0);

    __builtin_amdgcn_sched_barrier(0);
    __builtin_amdgcn_s_barrier();
    __builtin_amdgcn_sched_barrier(0);
  }

#pragma unroll
  for (int m = 0; m < 4; ++m) {
    const int grow0 = m0 + wm + m * 16 + lg * 4;
#pragma unroll
    for (int n = 0; n < 2; ++n) {
      const int gcol = n0 + wn + n * 16 + lr;
      const float bv = bias[gcol];
      if constexpr (MODE == 0) {
        int which = (gcol >= 1536) ? 2 : (gcol >= 768 ? 1 : 0);
        int rem = gcol - which * 768;
        int bh = (grow0 >> 10) * 12 + (rem >> 6);
        if (which == 2) {
          int s0 = grow0 & 1023;
          int colb = (s0 & ~63) | kappa(s0 & 63);
          ushort4 pk;
          pk.x = f2bf(acc[m][n][0] + bv);
          pk.y = f2bf(acc[m][n][1] + bv);
          pk.z = f2bf(acc[m][n][2] + bv);
          pk.w = f2bf(acc[m][n][3] + bv);
          *(ushort4*)&ovt[((size_t)bh << 16) + (size_t)(rem & 63) * 1024 + colb] = pk;
        } else if (which == 0) {
#pragma unroll
          for (int r = 0; r < 4; ++r) {
            int s = (grow0 & 1023) + r;
            oq[((size_t)bh << 17) + s * 128 + (rem & 63)] =
                f2bf((acc[m][n][r] + bv) * 0.18033688f);
          }
        } else {
#pragma unroll
          for (int r = 0; r < 4; ++r) {
            int s = (grow0 & 1023) + r;
            ok[((size_t)bh << 16) + s * 64 + (rem & 63)] = f2bf(acc[m][n][r] + bv);
          }
        }
      } else {
#pragma unroll
        for (int r = 0; r < 4; ++r)
          ofp[(size_t)(grow0 + r) * 768 + gcol] = acc[m][n][r] + bv;
      }
    }
  }
}

// ---------------------------------------------------------------- flash attention
// grid (96 heads, 8 q-tiles); block 256 = 4 waves x 32 q-rows.
__global__ __launch_bounds__(256, 2) void attn_kernel(
    const u16* __restrict__ qb, const u16* __restrict__ kb,
    const u16* __restrict__ vtb, u16* __restrict__ ao) {
  __shared__ u16 Ks[2][4096];
  __shared__ u16 Vs[2][4096];

  const int tid = threadIdx.x;
  const int lane = tid & 63, wave = tid >> 6;
  const int lr = lane & 15, lg = lane >> 4;
  const int bh = blockIdx.x;
  const int q0 = blockIdx.y * 128 + wave * 32;
  const size_t hb2 = (size_t)bh << 17;
  const size_t hbv = (size_t)bh << 16;

  bf16x8 qf[2][4];
#pragma unroll
  for (int m = 0; m < 2; ++m)
#pragma unroll
    for (int kf = 0; kf < 4; ++kf)
      qf[m][kf] = *(const bf16x8*)(qb + hb2 + (size_t)(q0 + m * 16 + lr) * 128 + kf * 32 + lg * 8);

  f32x4 sacW[2][2] = {};
#pragma unroll
  for (int h = 0; h < 2; ++h) {
    bf16x8 kwf = onehot8(h * 16 + lr - lg * 8);
#pragma unroll
    for (int m = 0; m < 2; ++m)
      sacW[m][h] = __builtin_amdgcn_mfma_f32_16x16x32_bf16(kwf, qf[m][2], sacW[m][h], 0, 0, 0);
  }

  float lsum[2] = {};
  f32x4 acco[2][4] = {};

  const u16* kp[2];
  const u16* vp[2];
#pragma unroll
  for (int i = 0; i < 2; ++i) {
    int c = tid + i * 256;
    int row = c >> 3, pp = c & 7;
    int pl = pp ^ (row & 7);
    kp[i] = kb + hbv + (size_t)row * 64 + pl * 8;
    vp[i] = vtb + hbv + (size_t)row * 1024 + pl * 8;
  }

  auto stage = [&](int bi) {
#pragma unroll
    for (int i = 0; i < 2; ++i) {
      int c = tid + i * 256;
      GLD16(kp[i], &Ks[bi][c * 8]);
      GLD16(vp[i], &Vs[bi][c * 8]);
      kp[i] += 4096;
      vp[i] += 64;
    }
  };

  stage(0);

#pragma unroll 1
  for (int t = 0; t < 16; ++t) {
    const int cur = t & 1;
    if (t < 15) {
      stage(cur ^ 1);
      asm volatile("s_waitcnt vmcnt(4)" ::: "memory");
    } else {
      asm volatile("s_waitcnt vmcnt(0)" ::: "memory");
    }
    __builtin_amdgcn_sched_barrier(0);
    __builtin_amdgcn_s_barrier();
    __builtin_amdgcn_sched_barrier(0);

    bf16x8 khf[2];
#pragma unroll
    for (int h = 0; h < 2; ++h) khf[h] = onehot8(2 * t + h - lg * 8);

    f32x4 sac[2][4];
#pragma unroll
    for (int m = 0; m < 2; ++m)
#pragma unroll
      for (int f = 0; f < 4; ++f) sac[m][f] = sacW[m][f & 1];
    __builtin_amdgcn_s_setprio(1);
#pragma unroll
    for (int kf = 0; kf < 2; ++kf) {
#pragma unroll
      for (int f = 0; f < 4; ++f) {
        int row = f * 16 + lr;
        bf16x8 kv = *(const bf16x8*)&Ks[cur][(row * 64 + kf * 32 + lg * 8) ^ ((row & 7) << 3)];
#pragma unroll
        for (int m = 0; m < 2; ++m)
          sac[m][f] = __builtin_amdgcn_mfma_f32_16x16x32_bf16(kv, qf[m][kf], sac[m][f], 0, 0, 0);
      }
    }
#pragma unroll
    for (int f = 0; f < 4; ++f)
#pragma unroll
      for (int m = 0; m < 2; ++m)
        sac[m][f] = __builtin_amdgcn_mfma_f32_16x16x32_bf16(khf[f >> 1], qf[m][3], sac[m][f], 0, 0, 0);
    __builtin_amdgcn_s_setprio(0);

    bf16x8 paf[2][2];
#pragma unroll
    for (int m = 0; m < 2; ++m) {
      union { u32 w[4]; bf16x8 v; } wa, wb;
#pragma unroll
      for (int f = 0; f < 4; ++f) {
        float p0 = __builtin_amdgcn_exp2f(sac[m][f][0]);
        float p1 = __builtin_amdgcn_exp2f(sac[m][f][1]);
        float p2 = __builtin_amdgcn_exp2f(sac[m][f][2]);
        float p3 = __builtin_amdgcn_exp2f(sac[m][f][3]);
        lsum[m] += (p0 + p1) + (p2 + p3);
        u32 w0, w1;
        asm("v_cvt_pk_bf16_f32 %0, %1, %2" : "=v"(w0) : "v"(p0), "v"(p1));
        asm("v_cvt_pk_bf16_f32 %0, %1, %2" : "=v"(w1) : "v"(p2), "v"(p3));
        if (f < 2) { wa.w[f * 2] = w0; wa.w[f * 2 + 1] = w1; }
        else       { wb.w[(f - 2) * 2] = w0; wb.w[(f - 2) * 2 + 1] = w1; }
      }
      paf[m][0] = wa.v;
      paf[m][1] = wb.v;
    }

    __builtin_amdgcn_s_setprio(1);
#pragma unroll
    for (int kf = 0; kf < 2; ++kf) {
#pragma unroll
      for (int fd = 0; fd < 4; ++fd) {
        int drow = fd * 16 + lr;
        bf16x8 vv = *(const bf16x8*)&Vs[cur][(drow * 64 + kf * 32 + lg * 8) ^ ((drow & 7) << 3)];
#pragma unroll
        for (int m = 0; m < 2; ++m)
          acco[m][fd] = __builtin_amdgcn_mfma_f32_16x16x32_bf16(paf[m][kf], vv, acco[m][fd], 0, 0, 0);
      }
    }
    __builtin_amdgcn_s_setprio(0);

    __builtin_amdgcn_sched_barrier(0);
    __builtin_amdgcn_s_barrier();
    __builtin_amdgcn_sched_barrier(0);
  }

#pragma unroll
  for (int m = 0; m < 2; ++m) {
    float s = lsum[m];
    s += __shfl_xor(s, 16);
    s += __shfl_xor(s, 32);
    float inv = 1.0f / s;
#pragma unroll
    for (int r = 0; r < 4; ++r) {
      int src = (lane & 48) + ((lane & 48) >> 2) + r;
      float invr = __shfl(inv, src);
      int gq = q0 + m * 16 + lg * 4 + r;
#pragma unroll
      for (int fd = 0; fd < 4; ++fd)
        ao[hbv + (size_t)gq * 64 + fd * 16 + lr] = f2bf(acco[m][fd][r] * invr);
    }
  }
}

// ---------------------------------------------------------------- launch
extern "C" void kernel_launch(void* const* d_in, const int* in_sizes, int n_in,
                              void* d_out, int out_size, void* d_ws, size_t ws_size,
                              hipStream_t stream) {
  const float* x = (const float*)d_in[0];
  const float* qkv_w = (const float*)d_in[1];
  const float* qkv_b = (const float*)d_in[2];
  const float* proj_w = (const float*)d_in[3];
  const float* proj_b = (const float*)d_in[4];
  const float* rel_pos_h = (const float*)d_in[5];
  const float* rel_pos_w = (const float*)d_in[6];
  float* out = (float*)d_out;

  char* ws = (char*)d_ws;
  u16* x_bf = (u16*)(ws + 0);              // 12,582,912 B (reused as attn out)
  u16* qkvw_bf = (u16*)(ws + 12582912);    //  3,538,944
  u16* projw_bf = (u16*)(ws + 16121856);   //  1,179,648
  u16* qbuf2 = (u16*)(ws + 17301504);      // 25,165,824 (96x1024x128, aug Q)
  u16* kbuf = (u16*)(ws + 42467328);       // 12,582,912 (96x1024x64)
  u16* vtbuf = (u16*)(ws + 55050240);      // 12,582,912
  u16* tbl = (u16*)(ws + 67633152);        //     16,384 -> total 67,649,536
  u16* aobuf = x_bf;                        // alias: x_bf dead after QKV gemm

  prep_kernel<<<8456, 256, 0, stream>>>(x, qkv_w, proj_w, rel_pos_h, rel_pos_w,
                                        x_bf, qkvw_bf, projw_bf, tbl);

  gemm256<0><<<dim3(9, 32), 512, 0, stream>>>(x_bf, qkvw_bf, qkv_b, qbuf2, kbuf, vtbuf, nullptr);

  pgemm_kernel<<<384, 256, 0, stream>>>(qbuf2, tbl, qbuf2);

  attn_kernel<<<dim3(96, 8), 256, 0, stream>>>(qbuf2, kbuf, vtbuf, aobuf);

  gemm128<1><<<dim3(6, 64), 512, 0, stream>>>(aobuf, projw_bf, proj_b, nullptr, nullptr, nullptr, out);
}

// Round 19
// 119.693 us; speedup vs baseline: 1.1260x; 1.1260x over previous
//
#include <hip/hip_runtime.h>

using u16 = unsigned short;
using u32 = unsigned int;
typedef __attribute__((ext_vector_type(8))) short bf16x8;
typedef __attribute__((ext_vector_type(4))) float f32x4;

__device__ __forceinline__ float bf2f(u32 h) {
  union { u32 u; float f; } c; c.u = h << 16; return c.f;
}
__device__ __forceinline__ u16 f2bf(float f) {
  union { float f; u32 u; } c; c.f = f;
  u32 u = c.u;
  u32 r = (u + 0x7FFFu + ((u >> 16) & 1u)) >> 16;
  return (u16)r;
}

#define GLD16(gsrc, ldst)                                                      \
  __builtin_amdgcn_global_load_lds(                                            \
      (const __attribute__((address_space(1))) unsigned int*)(gsrc),           \
      (__attribute__((address_space(3))) unsigned int*)(ldst), 16, 0, 0)

// kappa: virtual key order inside a 64-key tile so PV's A-frag is the natural
// register layout of the swapped QK^T output.
__device__ __forceinline__ int kappa(int ss) {
  return (ss & 0x23) | ((ss & 0x10) >> 2) | ((ss & 0x0C) << 1);
}

// one-hot bf16x8 A-frag word builder: hot halfword c in [0,8), zero otherwise
__device__ __forceinline__ bf16x8 onehot8(int c) {
  union { u32 w[4]; bf16x8 v; } u;
  u32 hv = (c & 1) ? 0x3F800000u : 0x3F80u;
#pragma unroll
  for (int k = 0; k < 4; ++k) u.w[k] = ((c >> 1) == k) ? hv : 0u;
  return u.v;
}

// ---------------------------------------------------------------- prep
__global__ void prep_kernel(const float* __restrict__ x, const float* __restrict__ qw,
                            const float* __restrict__ pw, const float* __restrict__ rph,
                            const float* __restrict__ rpw, u16* __restrict__ xb,
                            u16* __restrict__ qwb, u16* __restrict__ pwb,
                            u16* __restrict__ tbl) {
  int i = blockIdx.x * 256 + threadIdx.x;   // 2,164,736 total quads
  const float* src;
  u16* dst;
  int j;
  if (i < 1572864) { src = x; dst = xb; j = i; }
  else if (i < 2015232) { src = qw; dst = qwb; j = i - 1572864; }
  else if (i < 2162688) { src = pw; dst = pwb; j = i - 2015232; }
  else {
    int b = (i - 2162688) * 4;
    ushort4 o;
#pragma unroll
    for (int k = 0; k < 4; ++k) {
      int idx = b + k, row = idx >> 6, d = idx & 63;
      float v = 0.f;
      if (row < 63) v = rph[row * 64 + d];
      else if (row >= 64 && row < 127) v = rpw[(row - 64) * 64 + d];
      ((u16*)&o)[k] = f2bf(v * 8.0f);
    }
    *(ushort4*)&tbl[b] = o;
    return;
  }
  float4 v = *(const float4*)(src + j * 4);
  ushort4 o;
  o.x = f2bf(v.x); o.y = f2bf(v.y); o.z = f2bf(v.z); o.w = f2bf(v.w);
  *(ushort4*)(dst + j * 4) = o;
}

// ---------------------------------------------------------------- P gemm
__global__ __launch_bounds__(256, 2) void pgemm_kernel(
    const u16* __restrict__ A, const u16* __restrict__ tbl, u16* __restrict__ Q2) {
  __shared__ u16 Bs[128 * 64];
  const int tid = threadIdx.x;
  const int lane = tid & 63, wave = tid >> 6;
  const int lr = lane & 15, lg = lane >> 4;
  const int m0 = blockIdx.x * 256;
  const int wm = (wave >> 1) * 64, wn = (wave & 1) * 64;

#pragma unroll
  for (int i = 0; i < 4; ++i) {
    int c = tid + i * 256;
    int row = c >> 3, pp = c & 7;
    int pl = pp ^ (row & 7);  // pre-swizzled source, linear LDS dest
    GLD16(tbl + row * 64 + pl * 8, &Bs[c * 8]);
  }
  __syncthreads();

  bf16x8 b[4][2];
#pragma unroll
  for (int n = 0; n < 4; ++n) {
    int row = wn + n * 16 + lr;
#pragma unroll
    for (int kf = 0; kf < 2; ++kf)
      b[n][kf] = *(const bf16x8*)&Bs[(row * 64 + kf * 32 + lg * 8) ^ ((row & 7) << 3)];
  }

#pragma unroll
  for (int tt = 0; tt < 2; ++tt) {
    bf16x8 a[4][2];
#pragma unroll
    for (int m = 0; m < 4; ++m) {
      int g = m0 + tt * 128 + wm + m * 16 + lr;
#pragma unroll
      for (int kf = 0; kf < 2; ++kf)
        a[m][kf] = *(const bf16x8*)(A + (size_t)g * 128 + kf * 32 + lg * 8);
    }
    f32x4 acc[4][4] = {};
#pragma unroll
    for (int kf = 0; kf < 2; ++kf)
#pragma unroll
      for (int m = 0; m < 4; ++m)
#pragma unroll
        for (int n = 0; n < 4; ++n)
          acc[m][n] = __builtin_amdgcn_mfma_f32_16x16x32_bf16(a[m][kf], b[n][kf], acc[m][n], 0, 0, 0);

#pragma unroll
    for (int m = 0; m < 4; ++m)
#pragma unroll
      for (int n = 0; n < 4; ++n) {
        const int col = wn + n * 16 + lr;
#pragma unroll
        for (int r = 0; r < 4; ++r) {
          const int g = m0 + tt * 128 + wm + m * 16 + lg * 4 + r;
          const int s = g & 1023;
          const int hq = s >> 5, w = s & 31;
          u16 hv = f2bf(acc[m][n][r]);
          if (col < 64) {
            int kh = hq + 31 - col;
            if ((unsigned)kh < 32u) Q2[(size_t)g * 128 + 96 + kh] = hv;
          } else {
            int kw = w + 95 - col;
            if ((unsigned)kw < 32u) Q2[(size_t)g * 128 + 64 + kw] = hv;
          }
        }
      }
  }
}

// ---------------------------------------------------------------- GEMM (QKV, proven)
// 128x128 tile, BK=64, 512 threads / 8 waves (wave tile 64x32), XOR-swizzled
// LDS, XCD block swizzle, counted vmcnt, loop-carried staging pointers.
// q stride-128 (aug, pre-scaled 0.125*log2e); k stride-64; v^T kappa.
__global__ __launch_bounds__(512, 2) void gemm128(
    const u16* __restrict__ A, const u16* __restrict__ B,
    const float* __restrict__ bias, u16* __restrict__ oq, u16* __restrict__ ok,
    u16* __restrict__ ovt) {
  __shared__ u16 As[2][128 * 64];
  __shared__ u16 Bs[2][128 * 64];
  const int tid = threadIdx.x;
  const int lane = tid & 63, wave = tid >> 6;
  const int lr = lane & 15, lg = lane >> 4;

  const int nbx = 18;
  const int nwg = nbx * 64;
  int id = blockIdx.y * nbx + blockIdx.x;
  int nid = (id & 7) * (nwg >> 3) + (id >> 3);
  const int m0 = (nid / nbx) * 128, n0 = (nid % nbx) * 128;
  const int wm = (wave >> 2) * 64, wn = (wave & 3) * 32;

  f32x4 acc[4][2] = {};

  int aoff[4][2], boff[2][2];
#pragma unroll
  for (int m = 0; m < 4; ++m) {
    int row = wm + m * 16 + lr;
#pragma unroll
    for (int kf = 0; kf < 2; ++kf)
      aoff[m][kf] = (row * 64 + kf * 32 + lg * 8) ^ ((row & 7) << 3);
  }
#pragma unroll
  for (int n = 0; n < 2; ++n) {
    int row = wn + n * 16 + lr;
#pragma unroll
    for (int kf = 0; kf < 2; ++kf)
      boff[n][kf] = (row * 64 + kf * 32 + lg * 8) ^ ((row & 7) << 3);
  }

  const u16* ap[2];
  const u16* bp[2];
#pragma unroll
  for (int i = 0; i < 2; ++i) {
    int c = tid + i * 512;          // 1024 chunks = 128 rows x 8
    int row = c >> 3, pp = c & 7;
    int pl = pp ^ (row & 7);        // pre-swizzled global source, linear LDS dest
    ap[i] = A + (size_t)(m0 + row) * 768 + pl * 8;
    bp[i] = B + (size_t)(n0 + row) * 768 + pl * 8;
  }

  auto stage = [&](int bi) {
#pragma unroll
    for (int i = 0; i < 2; ++i) {
      int c = tid + i * 512;
      GLD16(ap[i], &As[bi][c * 8]);
      GLD16(bp[i], &Bs[bi][c * 8]);
      ap[i] += 64;
      bp[i] += 64;
    }
  };

  stage(0);
#pragma unroll 1
  for (int t = 0; t < 12; ++t) {
    const int cur = t & 1;
    if (t < 11) {
      stage(cur ^ 1);
      asm volatile("s_waitcnt vmcnt(4)" ::: "memory");
    } else {
      asm volatile("s_waitcnt vmcnt(0)" ::: "memory");
    }
    __builtin_amdgcn_sched_barrier(0);
    __builtin_amdgcn_s_barrier();
    __builtin_amdgcn_sched_barrier(0);

    bf16x8 a[4][2], b[2][2];
#pragma unroll
    for (int m = 0; m < 4; ++m)
#pragma unroll
      for (int kf = 0; kf < 2; ++kf)
        a[m][kf] = *(const bf16x8*)&As[cur][aoff[m][kf]];
#pragma unroll
    for (int n = 0; n < 2; ++n)
#pragma unroll
      for (int kf = 0; kf < 2; ++kf)
        b[n][kf] = *(const bf16x8*)&Bs[cur][boff[n][kf]];
    __builtin_amdgcn_s_setprio(1);
#pragma unroll
    for (int kf = 0; kf < 2; ++kf)
#pragma unroll
      for (int m = 0; m < 4; ++m)
#pragma unroll
        for (int n = 0; n < 2; ++n)
          acc[m][n] = __builtin_amdgcn_mfma_f32_16x16x32_bf16(a[m][kf], b[n][kf], acc[m][n], 0, 0, 0);
    __builtin_amdgcn_s_setprio(0);

    __builtin_amdgcn_sched_barrier(0);
    __builtin_amdgcn_s_barrier();
    __builtin_amdgcn_sched_barrier(0);
  }

#pragma unroll
  for (int m = 0; m < 4; ++m) {
    const int grow0 = m0 + wm + m * 16 + lg * 4;
#pragma unroll
    for (int n = 0; n < 2; ++n) {
      const int gcol = n0 + wn + n * 16 + lr;
      const float bv = bias[gcol];
      int which = (gcol >= 1536) ? 2 : (gcol >= 768 ? 1 : 0);
      int rem = gcol - which * 768;
      int bh = (grow0 >> 10) * 12 + (rem >> 6);
      if (which == 2) {
        int s0 = grow0 & 1023;
        int colb = (s0 & ~63) | kappa(s0 & 63);
        ushort4 pk;
        pk.x = f2bf(acc[m][n][0] + bv);
        pk.y = f2bf(acc[m][n][1] + bv);
        pk.z = f2bf(acc[m][n][2] + bv);
        pk.w = f2bf(acc[m][n][3] + bv);
        *(ushort4*)&ovt[((size_t)bh << 16) + (size_t)(rem & 63) * 1024 + colb] = pk;
      } else if (which == 0) {
#pragma unroll
        for (int r = 0; r < 4; ++r) {
          int s = (grow0 & 1023) + r;
          oq[((size_t)bh << 17) + s * 128 + (rem & 63)] =
              f2bf((acc[m][n][r] + bv) * 0.18033688f);
        }
      } else {
#pragma unroll
        for (int r = 0; r < 4; ++r) {
          int s = (grow0 & 1023) + r;
          ok[((size_t)bh << 16) + s * 64 + (rem & 63)] = f2bf(acc[m][n][r] + bv);
        }
      }
    }
  }
}

// ---------------------------------------------------------------- GEMM (proj)
// 64x128 tile, BK=64, 512 threads / 8 waves (wave tile 32x32 = 2Mx4N strips).
// 48 KB LDS -> 3 blocks/CU; grid 768 = EXACTLY one full round (100% fill,
// was 75% at 128x128/384 blocks). Same 2-phase counted-vmcnt(3) structure.
// A gathered from attn-out (96,1024,64); fp32 output.
__global__ __launch_bounds__(512, 2) void gemmP(
    const u16* __restrict__ A, const u16* __restrict__ B,
    const float* __restrict__ bias, float* __restrict__ ofp) {
  __shared__ u16 As[2][64 * 64];
  __shared__ u16 Bs[2][128 * 64];
  const int tid = threadIdx.x;
  const int lane = tid & 63, wave = tid >> 6;
  const int lr = lane & 15, lg = lane >> 4;

  const int nbx = 6;
  const int nwg = nbx * 128;                 // 768, %8 == 0
  int id = blockIdx.y * nbx + blockIdx.x;
  int nid = (id & 7) * (nwg >> 3) + (id >> 3);
  const int m0 = (nid / nbx) * 64, n0 = (nid % nbx) * 128;
  const int wm = (wave >> 2) * 32, wn = (wave & 3) * 32;

  f32x4 acc[2][2] = {};

  int aoff[2][2], boff[2][2];
#pragma unroll
  for (int m = 0; m < 2; ++m) {
    int row = wm + m * 16 + lr;
#pragma unroll
    for (int kf = 0; kf < 2; ++kf)
      aoff[m][kf] = (row * 64 + kf * 32 + lg * 8) ^ ((row & 7) << 3);
  }
#pragma unroll
  for (int n = 0; n < 2; ++n) {
    int row = wn + n * 16 + lr;
#pragma unroll
    for (int kf = 0; kf < 2; ++kf)
      boff[n][kf] = (row * 64 + kf * 32 + lg * 8) ^ ((row & 7) << 3);
  }

  // staging: A 512 chunks (64 rows x 8) -> 1/thread; B 1024 -> 2/thread
  const u16* ap;
  const u16* bp[2];
  {
    int row = tid >> 3, pp = tid & 7;
    int pl = pp ^ (row & 7);
    int g = m0 + row;
    ap = A + ((size_t)((g >> 10) * 12) << 16) + (g & 1023) * 64 + pl * 8;
  }
#pragma unroll
  for (int i = 0; i < 2; ++i) {
    int c = tid + i * 512;
    int row = c >> 3, pp = c & 7;
    int pl = pp ^ (row & 7);
    bp[i] = B + (size_t)(n0 + row) * 768 + pl * 8;
  }

  auto stage = [&](int bi) {
    GLD16(ap, &As[bi][tid * 8]);
    GLD16(bp[0], &Bs[bi][tid * 8]);
    GLD16(bp[1], &Bs[bi][(tid + 512) * 8]);
    ap += 65536;                 // next 64-wide k-block of the head dim
    bp[0] += 64;
    bp[1] += 64;
  };

  stage(0);
#pragma unroll 1
  for (int t = 0; t < 12; ++t) {
    const int cur = t & 1;
    if (t < 11) {
      stage(cur ^ 1);
      asm volatile("s_waitcnt vmcnt(3)" ::: "memory");
    } else {
      asm volatile("s_waitcnt vmcnt(0)" ::: "memory");
    }
    __builtin_amdgcn_sched_barrier(0);
    __builtin_amdgcn_s_barrier();
    __builtin_amdgcn_sched_barrier(0);

    bf16x8 a[2][2], b[2][2];
#pragma unroll
    for (int m = 0; m < 2; ++m)
#pragma unroll
      for (int kf = 0; kf < 2; ++kf)
        a[m][kf] = *(const bf16x8*)&As[cur][aoff[m][kf]];
#pragma unroll
    for (int n = 0; n < 2; ++n)
#pragma unroll
      for (int kf = 0; kf < 2; ++kf)
        b[n][kf] = *(const bf16x8*)&Bs[cur][boff[n][kf]];
    __builtin_amdgcn_s_setprio(1);
#pragma unroll
    for (int kf = 0; kf < 2; ++kf)
#pragma unroll
      for (int m = 0; m < 2; ++m)
#pragma unroll
        for (int n = 0; n < 2; ++n)
          acc[m][n] = __builtin_amdgcn_mfma_f32_16x16x32_bf16(a[m][kf], b[n][kf], acc[m][n], 0, 0, 0);
    __builtin_amdgcn_s_setprio(0);

    __builtin_amdgcn_sched_barrier(0);
    __builtin_amdgcn_s_barrier();
    __builtin_amdgcn_sched_barrier(0);
  }

#pragma unroll
  for (int m = 0; m < 2; ++m) {
    const int grow0 = m0 + wm + m * 16 + lg * 4;
#pragma unroll
    for (int n = 0; n < 2; ++n) {
      const int gcol = n0 + wn + n * 16 + lr;
      const float bv = bias[gcol];
#pragma unroll
      for (int r = 0; r < 4; ++r)
        ofp[(size_t)(grow0 + r) * 768 + gcol] = acc[m][n][r] + bv;
    }
  }
}

// ---------------------------------------------------------------- flash attention
// grid (96 heads, 8 q-tiles); block 256 = 4 waves x 32 q-rows.
__global__ __launch_bounds__(256, 2) void attn_kernel(
    const u16* __restrict__ qb, const u16* __restrict__ kb,
    const u16* __restrict__ vtb, u16* __restrict__ ao) {
  __shared__ u16 Ks[2][4096];
  __shared__ u16 Vs[2][4096];

  const int tid = threadIdx.x;
  const int lane = tid & 63, wave = tid >> 6;
  const int lr = lane & 15, lg = lane >> 4;
  const int bh = blockIdx.x;
  const int q0 = blockIdx.y * 128 + wave * 32;
  const size_t hb2 = (size_t)bh << 17;
  const size_t hbv = (size_t)bh << 16;

  bf16x8 qf[2][4];
#pragma unroll
  for (int m = 0; m < 2; ++m)
#pragma unroll
    for (int kf = 0; kf < 4; ++kf)
      qf[m][kf] = *(const bf16x8*)(qb + hb2 + (size_t)(q0 + m * 16 + lr) * 128 + kf * 32 + lg * 8);

  f32x4 sacW[2][2] = {};
#pragma unroll
  for (int h = 0; h < 2; ++h) {
    bf16x8 kwf = onehot8(h * 16 + lr - lg * 8);
#pragma unroll
    for (int m = 0; m < 2; ++m)
      sacW[m][h] = __builtin_amdgcn_mfma_f32_16x16x32_bf16(kwf, qf[m][2], sacW[m][h], 0, 0, 0);
  }

  float lsum[2] = {};
  f32x4 acco[2][4] = {};

  const u16* kp[2];
  const u16* vp[2];
#pragma unroll
  for (int i = 0; i < 2; ++i) {
    int c = tid + i * 256;
    int row = c >> 3, pp = c & 7;
    int pl = pp ^ (row & 7);
    kp[i] = kb + hbv + (size_t)row * 64 + pl * 8;
    vp[i] = vtb + hbv + (size_t)row * 1024 + pl * 8;
  }

  auto stage = [&](int bi) {
#pragma unroll
    for (int i = 0; i < 2; ++i) {
      int c = tid + i * 256;
      GLD16(kp[i], &Ks[bi][c * 8]);
      GLD16(vp[i], &Vs[bi][c * 8]);
      kp[i] += 4096;
      vp[i] += 64;
    }
  };

  stage(0);

#pragma unroll 1
  for (int t = 0; t < 16; ++t) {
    const int cur = t & 1;
    if (t < 15) {
      stage(cur ^ 1);
      asm volatile("s_waitcnt vmcnt(4)" ::: "memory");
    } else {
      asm volatile("s_waitcnt vmcnt(0)" ::: "memory");
    }
    __builtin_amdgcn_sched_barrier(0);
    __builtin_amdgcn_s_barrier();
    __builtin_amdgcn_sched_barrier(0);

    bf16x8 khf[2];
#pragma unroll
    for (int h = 0; h < 2; ++h) khf[h] = onehot8(2 * t + h - lg * 8);

    f32x4 sac[2][4];
#pragma unroll
    for (int m = 0; m < 2; ++m)
#pragma unroll
      for (int f = 0; f < 4; ++f) sac[m][f] = sacW[m][f & 1];
    __builtin_amdgcn_s_setprio(1);
#pragma unroll
    for (int kf = 0; kf < 2; ++kf) {
#pragma unroll
      for (int f = 0; f < 4; ++f) {
        int row = f * 16 + lr;
        bf16x8 kv = *(const bf16x8*)&Ks[cur][(row * 64 + kf * 32 + lg * 8) ^ ((row & 7) << 3)];
#pragma unroll
        for (int m = 0; m < 2; ++m)
          sac[m][f] = __builtin_amdgcn_mfma_f32_16x16x32_bf16(kv, qf[m][kf], sac[m][f], 0, 0, 0);
      }
    }
#pragma unroll
    for (int f = 0; f < 4; ++f)
#pragma unroll
      for (int m = 0; m < 2; ++m)
        sac[m][f] = __builtin_amdgcn_mfma_f32_16x16x32_bf16(khf[f >> 1], qf[m][3], sac[m][f], 0, 0, 0);
    __builtin_amdgcn_s_setprio(0);

    bf16x8 paf[2][2];
#pragma unroll
    for (int m = 0; m < 2; ++m) {
      union { u32 w[4]; bf16x8 v; } wa, wb;
#pragma unroll
      for (int f = 0; f < 4; ++f) {
        float p0 = __builtin_amdgcn_exp2f(sac[m][f][0]);
        float p1 = __builtin_amdgcn_exp2f(sac[m][f][1]);
        float p2 = __builtin_amdgcn_exp2f(sac[m][f][2]);
        float p3 = __builtin_amdgcn_exp2f(sac[m][f][3]);
        lsum[m] += (p0 + p1) + (p2 + p3);
        u32 w0, w1;
        asm("v_cvt_pk_bf16_f32 %0, %1, %2" : "=v"(w0) : "v"(p0), "v"(p1));
        asm("v_cvt_pk_bf16_f32 %0, %1, %2" : "=v"(w1) : "v"(p2), "v"(p3));
        if (f < 2) { wa.w[f * 2] = w0; wa.w[f * 2 + 1] = w1; }
        else       { wb.w[(f - 2) * 2] = w0; wb.w[(f - 2) * 2 + 1] = w1; }
      }
      paf[m][0] = wa.v;
      paf[m][1] = wb.v;
    }

    __builtin_amdgcn_s_setprio(1);
#pragma unroll
    for (int kf = 0; kf < 2; ++kf) {
#pragma unroll
      for (int fd = 0; fd < 4; ++fd) {
        int drow = fd * 16 + lr;
        bf16x8 vv = *(const bf16x8*)&Vs[cur][(drow * 64 + kf * 32 + lg * 8) ^ ((drow & 7) << 3)];
#pragma unroll
        for (int m = 0; m < 2; ++m)
          acco[m][fd] = __builtin_amdgcn_mfma_f32_16x16x32_bf16(paf[m][kf], vv, acco[m][fd], 0, 0, 0);
      }
    }
    __builtin_amdgcn_s_setprio(0);

    __builtin_amdgcn_sched_barrier(0);
    __builtin_amdgcn_s_barrier();
    __builtin_amdgcn_sched_barrier(0);
  }

#pragma unroll
  for (int m = 0; m < 2; ++m) {
    float s = lsum[m];
    s += __shfl_xor(s, 16);
    s += __shfl_xor(s, 32);
    float inv = 1.0f / s;
#pragma unroll
    for (int r = 0; r < 4; ++r) {
      int src = (lane & 48) + ((lane & 48) >> 2) + r;
      float invr = __shfl(inv, src);
      int gq = q0 + m * 16 + lg * 4 + r;
#pragma unroll
      for (int fd = 0; fd < 4; ++fd)
        ao[hbv + (size_t)gq * 64 + fd * 16 + lr] = f2bf(acco[m][fd][r] * invr);
    }
  }
}

// ---------------------------------------------------------------- launch
extern "C" void kernel_launch(void* const* d_in, const int* in_sizes, int n_in,
                              void* d_out, int out_size, void* d_ws, size_t ws_size,
                              hipStream_t stream) {
  const float* x = (const float*)d_in[0];
  const float* qkv_w = (const float*)d_in[1];
  const float* qkv_b = (const float*)d_in[2];
  const float* proj_w = (const float*)d_in[3];
  const float* proj_b = (const float*)d_in[4];
  const float* rel_pos_h = (const float*)d_in[5];
  const float* rel_pos_w = (const float*)d_in[6];
  float* out = (float*)d_out;

  char* ws = (char*)d_ws;
  u16* x_bf = (u16*)(ws + 0);              // 12,582,912 B (reused as attn out)
  u16* qkvw_bf = (u16*)(ws + 12582912);    //  3,538,944
  u16* projw_bf = (u16*)(ws + 16121856);   //  1,179,648
  u16* qbuf2 = (u16*)(ws + 17301504);      // 25,165,824 (96x1024x128, aug Q)
  u16* kbuf = (u16*)(ws + 42467328);       // 12,582,912 (96x1024x64)
  u16* vtbuf = (u16*)(ws + 55050240);      // 12,582,912
  u16* tbl = (u16*)(ws + 67633152);        //     16,384 -> total 67,649,536
  u16* aobuf = x_bf;                        // alias: x_bf dead after QKV gemm

  prep_kernel<<<8456, 256, 0, stream>>>(x, qkv_w, proj_w, rel_pos_h, rel_pos_w,
                                        x_bf, qkvw_bf, projw_bf, tbl);

  gemm128<<<dim3(18, 64), 512, 0, stream>>>(x_bf, qkvw_bf, qkv_b, qbuf2, kbuf, vtbuf);

  pgemm_kernel<<<384, 256, 0, stream>>>(qbuf2, tbl, qbuf2);

  attn_kernel<<<dim3(96, 8), 256, 0, stream>>>(qbuf2, kbuf, vtbuf, aobuf);

  gemmP<<<dim3(6, 128), 512, 0, stream>>>(aobuf, projw_bf, proj_b, out);
}

// Round 20
// 118.290 us; speedup vs baseline: 1.1393x; 1.0119x over previous
//
#include <hip/hip_runtime.h>

using u16 = unsigned short;
using u32 = unsigned int;
typedef __attribute__((ext_vector_type(8))) short bf16x8;
typedef __attribute__((ext_vector_type(4))) float f32x4;

__device__ __forceinline__ float bf2f(u32 h) {
  union { u32 u; float f; } c; c.u = h << 16; return c.f;
}
__device__ __forceinline__ u16 f2bf(float f) {
  union { float f; u32 u; } c; c.f = f;
  u32 u = c.u;
  u32 r = (u + 0x7FFFu + ((u >> 16) & 1u)) >> 16;
  return (u16)r;
}

#define GLD16(gsrc, ldst)                                                      \
  __builtin_amdgcn_global_load_lds(                                            \
      (const __attribute__((address_space(1))) unsigned int*)(gsrc),           \
      (__attribute__((address_space(3))) unsigned int*)(ldst), 16, 0, 0)

// kappa: virtual key order inside a 64-key tile so PV's A-frag is the natural
// register layout of the swapped QK^T output.
__device__ __forceinline__ int kappa(int ss) {
  return (ss & 0x23) | ((ss & 0x10) >> 2) | ((ss & 0x0C) << 1);
}

// one-hot bf16x8 A-frag word builder: hot halfword c in [0,8), zero otherwise
__device__ __forceinline__ bf16x8 onehot8(int c) {
  union { u32 w[4]; bf16x8 v; } u;
  u32 hv = (c & 1) ? 0x3F800000u : 0x3F80u;
#pragma unroll
  for (int k = 0; k < 4; ++k) u.w[k] = ((c >> 1) == k) ? hv : 0u;
  return u.v;
}

// ---------------------------------------------------------------- prep
// Fused cvt x / qkv_w / proj_w / rel-pos table; grid-stride over 2,164,736
// quads with 2048 blocks (G11: cap blocks, stride the rest).
__global__ void prep_kernel(const float* __restrict__ x, const float* __restrict__ qw,
                            const float* __restrict__ pw, const float* __restrict__ rph,
                            const float* __restrict__ rpw, u16* __restrict__ xb,
                            u16* __restrict__ qwb, u16* __restrict__ pwb,
                            u16* __restrict__ tbl) {
#pragma unroll 1
  for (int i = blockIdx.x * 256 + threadIdx.x; i < 2164736; i += 2048 * 256) {
    const float* src;
    u16* dst;
    int j;
    if (i < 1572864) { src = x; dst = xb; j = i; }
    else if (i < 2015232) { src = qw; dst = qwb; j = i - 1572864; }
    else if (i < 2162688) { src = pw; dst = pwb; j = i - 2015232; }
    else {
      int b = (i - 2162688) * 4;
      ushort4 o;
#pragma unroll
      for (int k = 0; k < 4; ++k) {
        int idx = b + k, row = idx >> 6, d = idx & 63;
        float v = 0.f;
        if (row < 63) v = rph[row * 64 + d];
        else if (row >= 64 && row < 127) v = rpw[(row - 64) * 64 + d];
        ((u16*)&o)[k] = f2bf(v * 8.0f);
      }
      *(ushort4*)&tbl[b] = o;
      continue;
    }
    float4 v = *(const float4*)(src + j * 4);
    ushort4 o;
    o.x = f2bf(v.x); o.y = f2bf(v.y); o.z = f2bf(v.z); o.w = f2bf(v.w);
    *(ushort4*)(dst + j * 4) = o;
  }
}

// ---------------------------------------------------------------- P gemm
__global__ __launch_bounds__(256, 2) void pgemm_kernel(
    const u16* __restrict__ A, const u16* __restrict__ tbl, u16* __restrict__ Q2) {
  __shared__ u16 Bs[128 * 64];
  const int tid = threadIdx.x;
  const int lane = tid & 63, wave = tid >> 6;
  const int lr = lane & 15, lg = lane >> 4;
  const int m0 = blockIdx.x * 256;
  const int wm = (wave >> 1) * 64, wn = (wave & 1) * 64;

#pragma unroll
  for (int i = 0; i < 4; ++i) {
    int c = tid + i * 256;
    int row = c >> 3, pp = c & 7;
    int pl = pp ^ (row & 7);  // pre-swizzled source, linear LDS dest
    GLD16(tbl + row * 64 + pl * 8, &Bs[c * 8]);
  }
  __syncthreads();

  bf16x8 b[4][2];
#pragma unroll
  for (int n = 0; n < 4; ++n) {
    int row = wn + n * 16 + lr;
#pragma unroll
    for (int kf = 0; kf < 2; ++kf)
      b[n][kf] = *(const bf16x8*)&Bs[(row * 64 + kf * 32 + lg * 8) ^ ((row & 7) << 3)];
  }

#pragma unroll
  for (int tt = 0; tt < 2; ++tt) {
    bf16x8 a[4][2];
#pragma unroll
    for (int m = 0; m < 4; ++m) {
      int g = m0 + tt * 128 + wm + m * 16 + lr;
#pragma unroll
      for (int kf = 0; kf < 2; ++kf)
        a[m][kf] = *(const bf16x8*)(A + (size_t)g * 128 + kf * 32 + lg * 8);
    }
    f32x4 acc[4][4] = {};
#pragma unroll
    for (int kf = 0; kf < 2; ++kf)
#pragma unroll
      for (int m = 0; m < 4; ++m)
#pragma unroll
        for (int n = 0; n < 4; ++n)
          acc[m][n] = __builtin_amdgcn_mfma_f32_16x16x32_bf16(a[m][kf], b[n][kf], acc[m][n], 0, 0, 0);

#pragma unroll
    for (int m = 0; m < 4; ++m)
#pragma unroll
      for (int n = 0; n < 4; ++n) {
        const int col = wn + n * 16 + lr;
#pragma unroll
        for (int r = 0; r < 4; ++r) {
          const int g = m0 + tt * 128 + wm + m * 16 + lg * 4 + r;
          const int s = g & 1023;
          const int hq = s >> 5, w = s & 31;
          u16 hv = f2bf(acc[m][n][r]);
          if (col < 64) {
            int kh = hq + 31 - col;
            if ((unsigned)kh < 32u) Q2[(size_t)g * 128 + 96 + kh] = hv;
          } else {
            int kw = w + 95 - col;
            if ((unsigned)kw < 32u) Q2[(size_t)g * 128 + 64 + kw] = hv;
          }
        }
      }
  }
}

// ---------------------------------------------------------------- GEMM (QKV, proven)
// 128x128 tile, BK=64, 512 threads / 8 waves (wave tile 64x32), XOR-swizzled
// LDS, XCD block swizzle, counted vmcnt, loop-carried staging pointers.
// q stride-128 (aug, pre-scaled 0.125*log2e); k stride-64; v^T kappa.
__global__ __launch_bounds__(512, 2) void gemm128(
    const u16* __restrict__ A, const u16* __restrict__ B,
    const float* __restrict__ bias, u16* __restrict__ oq, u16* __restrict__ ok,
    u16* __restrict__ ovt) {
  __shared__ u16 As[2][128 * 64];
  __shared__ u16 Bs[2][128 * 64];
  const int tid = threadIdx.x;
  const int lane = tid & 63, wave = tid >> 6;
  const int lr = lane & 15, lg = lane >> 4;

  const int nbx = 18;
  const int nwg = nbx * 64;
  int id = blockIdx.y * nbx + blockIdx.x;
  int nid = (id & 7) * (nwg >> 3) + (id >> 3);
  const int m0 = (nid / nbx) * 128, n0 = (nid % nbx) * 128;
  const int wm = (wave >> 2) * 64, wn = (wave & 3) * 32;

  f32x4 acc[4][2] = {};

  int aoff[4][2], boff[2][2];
#pragma unroll
  for (int m = 0; m < 4; ++m) {
    int row = wm + m * 16 + lr;
#pragma unroll
    for (int kf = 0; kf < 2; ++kf)
      aoff[m][kf] = (row * 64 + kf * 32 + lg * 8) ^ ((row & 7) << 3);
  }
#pragma unroll
  for (int n = 0; n < 2; ++n) {
    int row = wn + n * 16 + lr;
#pragma unroll
    for (int kf = 0; kf < 2; ++kf)
      boff[n][kf] = (row * 64 + kf * 32 + lg * 8) ^ ((row & 7) << 3);
  }

  const u16* ap[2];
  const u16* bp[2];
#pragma unroll
  for (int i = 0; i < 2; ++i) {
    int c = tid + i * 512;          // 1024 chunks = 128 rows x 8
    int row = c >> 3, pp = c & 7;
    int pl = pp ^ (row & 7);        // pre-swizzled global source, linear LDS dest
    ap[i] = A + (size_t)(m0 + row) * 768 + pl * 8;
    bp[i] = B + (size_t)(n0 + row) * 768 + pl * 8;
  }

  auto stage = [&](int bi) {
#pragma unroll
    for (int i = 0; i < 2; ++i) {
      int c = tid + i * 512;
      GLD16(ap[i], &As[bi][c * 8]);
      GLD16(bp[i], &Bs[bi][c * 8]);
      ap[i] += 64;
      bp[i] += 64;
    }
  };

  stage(0);
#pragma unroll 1
  for (int t = 0; t < 12; ++t) {
    const int cur = t & 1;
    if (t < 11) {
      stage(cur ^ 1);
      asm volatile("s_waitcnt vmcnt(4)" ::: "memory");
    } else {
      asm volatile("s_waitcnt vmcnt(0)" ::: "memory");
    }
    __builtin_amdgcn_sched_barrier(0);
    __builtin_amdgcn_s_barrier();
    __builtin_amdgcn_sched_barrier(0);

    bf16x8 a[4][2], b[2][2];
#pragma unroll
    for (int m = 0; m < 4; ++m)
#pragma unroll
      for (int kf = 0; kf < 2; ++kf)
        a[m][kf] = *(const bf16x8*)&As[cur][aoff[m][kf]];
#pragma unroll
    for (int n = 0; n < 2; ++n)
#pragma unroll
      for (int kf = 0; kf < 2; ++kf)
        b[n][kf] = *(const bf16x8*)&Bs[cur][boff[n][kf]];
    __builtin_amdgcn_s_setprio(1);
#pragma unroll
    for (int kf = 0; kf < 2; ++kf)
#pragma unroll
      for (int m = 0; m < 4; ++m)
#pragma unroll
        for (int n = 0; n < 2; ++n)
          acc[m][n] = __builtin_amdgcn_mfma_f32_16x16x32_bf16(a[m][kf], b[n][kf], acc[m][n], 0, 0, 0);
    __builtin_amdgcn_s_setprio(0);

    __builtin_amdgcn_sched_barrier(0);
    __builtin_amdgcn_s_barrier();
    __builtin_amdgcn_sched_barrier(0);
  }

#pragma unroll
  for (int m = 0; m < 4; ++m) {
    const int grow0 = m0 + wm + m * 16 + lg * 4;
#pragma unroll
    for (int n = 0; n < 2; ++n) {
      const int gcol = n0 + wn + n * 16 + lr;
      const float bv = bias[gcol];
      int which = (gcol >= 1536) ? 2 : (gcol >= 768 ? 1 : 0);
      int rem = gcol - which * 768;
      int bh = (grow0 >> 10) * 12 + (rem >> 6);
      if (which == 2) {
        int s0 = grow0 & 1023;
        int colb = (s0 & ~63) | kappa(s0 & 63);
        ushort4 pk;
        pk.x = f2bf(acc[m][n][0] + bv);
        pk.y = f2bf(acc[m][n][1] + bv);
        pk.z = f2bf(acc[m][n][2] + bv);
        pk.w = f2bf(acc[m][n][3] + bv);
        *(ushort4*)&ovt[((size_t)bh << 16) + (size_t)(rem & 63) * 1024 + colb] = pk;
      } else if (which == 0) {
#pragma unroll
        for (int r = 0; r < 4; ++r) {
          int s = (grow0 & 1023) + r;
          oq[((size_t)bh << 17) + s * 128 + (rem & 63)] =
              f2bf((acc[m][n][r] + bv) * 0.18033688f);
        }
      } else {
#pragma unroll
        for (int r = 0; r < 4; ++r) {
          int s = (grow0 & 1023) + r;
          ok[((size_t)bh << 16) + s * 64 + (rem & 63)] = f2bf(acc[m][n][r] + bv);
        }
      }
    }
  }
}

// ---------------------------------------------------------------- GEMM (proj)
// 64x128 tile, BK=64, 512 threads / 8 waves; 48 KB LDS -> 3 blocks/CU;
// grid 768 = one full round. 2-phase counted-vmcnt(3).
__global__ __launch_bounds__(512, 2) void gemmP(
    const u16* __restrict__ A, const u16* __restrict__ B,
    const float* __restrict__ bias, float* __restrict__ ofp) {
  __shared__ u16 As[2][64 * 64];
  __shared__ u16 Bs[2][128 * 64];
  const int tid = threadIdx.x;
  const int lane = tid & 63, wave = tid >> 6;
  const int lr = lane & 15, lg = lane >> 4;

  const int nbx = 6;
  const int nwg = nbx * 128;                 // 768, %8 == 0
  int id = blockIdx.y * nbx + blockIdx.x;
  int nid = (id & 7) * (nwg >> 3) + (id >> 3);
  const int m0 = (nid / nbx) * 64, n0 = (nid % nbx) * 128;
  const int wm = (wave >> 2) * 32, wn = (wave & 3) * 32;

  f32x4 acc[2][2] = {};

  int aoff[2][2], boff[2][2];
#pragma unroll
  for (int m = 0; m < 2; ++m) {
    int row = wm + m * 16 + lr;
#pragma unroll
    for (int kf = 0; kf < 2; ++kf)
      aoff[m][kf] = (row * 64 + kf * 32 + lg * 8) ^ ((row & 7) << 3);
  }
#pragma unroll
  for (int n = 0; n < 2; ++n) {
    int row = wn + n * 16 + lr;
#pragma unroll
    for (int kf = 0; kf < 2; ++kf)
      boff[n][kf] = (row * 64 + kf * 32 + lg * 8) ^ ((row & 7) << 3);
  }

  const u16* ap;
  const u16* bp[2];
  {
    int row = tid >> 3, pp = tid & 7;
    int pl = pp ^ (row & 7);
    int g = m0 + row;
    ap = A + ((size_t)((g >> 10) * 12) << 16) + (g & 1023) * 64 + pl * 8;
  }
#pragma unroll
  for (int i = 0; i < 2; ++i) {
    int c = tid + i * 512;
    int row = c >> 3, pp = c & 7;
    int pl = pp ^ (row & 7);
    bp[i] = B + (size_t)(n0 + row) * 768 + pl * 8;
  }

  auto stage = [&](int bi) {
    GLD16(ap, &As[bi][tid * 8]);
    GLD16(bp[0], &Bs[bi][tid * 8]);
    GLD16(bp[1], &Bs[bi][(tid + 512) * 8]);
    ap += 65536;                 // next 64-wide k-block of the head dim
    bp[0] += 64;
    bp[1] += 64;
  };

  stage(0);
#pragma unroll 1
  for (int t = 0; t < 12; ++t) {
    const int cur = t & 1;
    if (t < 11) {
      stage(cur ^ 1);
      asm volatile("s_waitcnt vmcnt(3)" ::: "memory");
    } else {
      asm volatile("s_waitcnt vmcnt(0)" ::: "memory");
    }
    __builtin_amdgcn_sched_barrier(0);
    __builtin_amdgcn_s_barrier();
    __builtin_amdgcn_sched_barrier(0);

    bf16x8 a[2][2], b[2][2];
#pragma unroll
    for (int m = 0; m < 2; ++m)
#pragma unroll
      for (int kf = 0; kf < 2; ++kf)
        a[m][kf] = *(const bf16x8*)&As[cur][aoff[m][kf]];
#pragma unroll
    for (int n = 0; n < 2; ++n)
#pragma unroll
      for (int kf = 0; kf < 2; ++kf)
        b[n][kf] = *(const bf16x8*)&Bs[cur][boff[n][kf]];
    __builtin_amdgcn_s_setprio(1);
#pragma unroll
    for (int kf = 0; kf < 2; ++kf)
#pragma unroll
      for (int m = 0; m < 2; ++m)
#pragma unroll
        for (int n = 0; n < 2; ++n)
          acc[m][n] = __builtin_amdgcn_mfma_f32_16x16x32_bf16(a[m][kf], b[n][kf], acc[m][n], 0, 0, 0);
    __builtin_amdgcn_s_setprio(0);

    __builtin_amdgcn_sched_barrier(0);
    __builtin_amdgcn_s_barrier();
    __builtin_amdgcn_sched_barrier(0);
  }

#pragma unroll
  for (int m = 0; m < 2; ++m) {
    const int grow0 = m0 + wm + m * 16 + lg * 4;
#pragma unroll
    for (int n = 0; n < 2; ++n) {
      const int gcol = n0 + wn + n * 16 + lr;
      const float bv = bias[gcol];
#pragma unroll
      for (int r = 0; r < 4; ++r)
        ofp[(size_t)(grow0 + r) * 768 + gcol] = acc[m][n][r] + bv;
    }
  }
}

// ---------------------------------------------------------------- flash attention
// grid (96 heads, 8 q-tiles); block 256 = 4 waves x 32 q-rows.
// SINGLE barrier per tile with a 3-deep LDS rotation (48 KB -> 3 blocks/CU):
// iter t: vmcnt(4) [drains stage(t); only stage(t+1) in flight -- the loop
// body has NO other VMEM] -> barrier -> stage(t+2) into buf[(t+2)%3] ->
// compute buf[t%3]. stage(t+2) overwrites buf[(t-1)%3], whose reads all
// completed before this barrier; a sprinting wave issues stage(t+3) into
// buf[t%3] only after the NEXT barrier, which gates on compute(t) everywhere.
__global__ __launch_bounds__(256, 2) void attn_kernel(
    const u16* __restrict__ qb, const u16* __restrict__ kb,
    const u16* __restrict__ vtb, u16* __restrict__ ao) {
  __shared__ u16 Ks[3][4096];
  __shared__ u16 Vs[3][4096];

  const int tid = threadIdx.x;
  const int lane = tid & 63, wave = tid >> 6;
  const int lr = lane & 15, lg = lane >> 4;
  const int bh = blockIdx.x;
  const int q0 = blockIdx.y * 128 + wave * 32;
  const size_t hb2 = (size_t)bh << 17;
  const size_t hbv = (size_t)bh << 16;

  bf16x8 qf[2][4];
#pragma unroll
  for (int m = 0; m < 2; ++m)
#pragma unroll
    for (int kf = 0; kf < 4; ++kf)
      qf[m][kf] = *(const bf16x8*)(qb + hb2 + (size_t)(q0 + m * 16 + lr) * 128 + kf * 32 + lg * 8);

  f32x4 sacW[2][2] = {};
#pragma unroll
  for (int h = 0; h < 2; ++h) {
    bf16x8 kwf = onehot8(h * 16 + lr - lg * 8);
#pragma unroll
    for (int m = 0; m < 2; ++m)
      sacW[m][h] = __builtin_amdgcn_mfma_f32_16x16x32_bf16(kwf, qf[m][2], sacW[m][h], 0, 0, 0);
  }

  float lsum[2] = {};
  f32x4 acco[2][4] = {};

  const u16* kp[2];
  const u16* vp[2];
#pragma unroll
  for (int i = 0; i < 2; ++i) {
    int c = tid + i * 256;
    int row = c >> 3, pp = c & 7;
    int pl = pp ^ (row & 7);
    kp[i] = kb + hbv + (size_t)row * 64 + pl * 8;
    vp[i] = vtb + hbv + (size_t)row * 1024 + pl * 8;
  }

  auto stage = [&](int bi) {
#pragma unroll
    for (int i = 0; i < 2; ++i) {
      int c = tid + i * 256;
      GLD16(kp[i], &Ks[bi][c * 8]);
      GLD16(vp[i], &Vs[bi][c * 8]);
      kp[i] += 4096;
      vp[i] += 64;
    }
  };

  stage(0);
  stage(1);

#pragma unroll 1
  for (int t = 0; t < 16; ++t) {
    const int cur = t % 3;
    if (t < 15) {
      asm volatile("s_waitcnt vmcnt(4)" ::: "memory");
    } else {
      asm volatile("s_waitcnt vmcnt(0)" ::: "memory");
    }
    __builtin_amdgcn_sched_barrier(0);
    __builtin_amdgcn_s_barrier();        // single barrier per tile
    __builtin_amdgcn_sched_barrier(0);

    if (t < 14) stage((t + 2) % 3);

    bf16x8 khf[2];
#pragma unroll
    for (int h = 0; h < 2; ++h) khf[h] = onehot8(2 * t + h - lg * 8);

    f32x4 sac[2][4];
#pragma unroll
    for (int m = 0; m < 2; ++m)
#pragma unroll
      for (int f = 0; f < 4; ++f) sac[m][f] = sacW[m][f & 1];
    __builtin_amdgcn_s_setprio(1);
#pragma unroll
    for (int kf = 0; kf < 2; ++kf) {
#pragma unroll
      for (int f = 0; f < 4; ++f) {
        int row = f * 16 + lr;
        bf16x8 kv = *(const bf16x8*)&Ks[cur][(row * 64 + kf * 32 + lg * 8) ^ ((row & 7) << 3)];
#pragma unroll
        for (int m = 0; m < 2; ++m)
          sac[m][f] = __builtin_amdgcn_mfma_f32_16x16x32_bf16(kv, qf[m][kf], sac[m][f], 0, 0, 0);
      }
    }
#pragma unroll
    for (int f = 0; f < 4; ++f)
#pragma unroll
      for (int m = 0; m < 2; ++m)
        sac[m][f] = __builtin_amdgcn_mfma_f32_16x16x32_bf16(khf[f >> 1], qf[m][3], sac[m][f], 0, 0, 0);
    __builtin_amdgcn_s_setprio(0);

    bf16x8 paf[2][2];
#pragma unroll
    for (int m = 0; m < 2; ++m) {
      union { u32 w[4]; bf16x8 v; } wa, wb;
#pragma unroll
      for (int f = 0; f < 4; ++f) {
        float p0 = __builtin_amdgcn_exp2f(sac[m][f][0]);
        float p1 = __builtin_amdgcn_exp2f(sac[m][f][1]);
        float p2 = __builtin_amdgcn_exp2f(sac[m][f][2]);
        float p3 = __builtin_amdgcn_exp2f(sac[m][f][3]);
        lsum[m] += (p0 + p1) + (p2 + p3);
        u32 w0, w1;
        asm("v_cvt_pk_bf16_f32 %0, %1, %2" : "=v"(w0) : "v"(p0), "v"(p1));
        asm("v_cvt_pk_bf16_f32 %0, %1, %2" : "=v"(w1) : "v"(p2), "v"(p3));
        if (f < 2) { wa.w[f * 2] = w0; wa.w[f * 2 + 1] = w1; }
        else       { wb.w[(f - 2) * 2] = w0; wb.w[(f - 2) * 2 + 1] = w1; }
      }
      paf[m][0] = wa.v;
      paf[m][1] = wb.v;
    }

    __builtin_amdgcn_s_setprio(1);
#pragma unroll
    for (int kf = 0; kf < 2; ++kf) {
#pragma unroll
      for (int fd = 0; fd < 4; ++fd) {
        int drow = fd * 16 + lr;
        bf16x8 vv = *(const bf16x8*)&Vs[cur][(drow * 64 + kf * 32 + lg * 8) ^ ((drow & 7) << 3)];
#pragma unroll
        for (int m = 0; m < 2; ++m)
          acco[m][fd] = __builtin_amdgcn_mfma_f32_16x16x32_bf16(paf[m][kf], vv, acco[m][fd], 0, 0, 0);
      }
    }
    __builtin_amdgcn_s_setprio(0);
  }

#pragma unroll
  for (int m = 0; m < 2; ++m) {
    float s = lsum[m];
    s += __shfl_xor(s, 16);
    s += __shfl_xor(s, 32);
    float inv = 1.0f / s;
#pragma unroll
    for (int r = 0; r < 4; ++r) {
      int src = (lane & 48) + ((lane & 48) >> 2) + r;
      float invr = __shfl(inv, src);
      int gq = q0 + m * 16 + lg * 4 + r;
#pragma unroll
      for (int fd = 0; fd < 4; ++fd)
        ao[hbv + (size_t)gq * 64 + fd * 16 + lr] = f2bf(acco[m][fd][r] * invr);
    }
  }
}

// ---------------------------------------------------------------- launch
extern "C" void kernel_launch(void* const* d_in, const int* in_sizes, int n_in,
                              void* d_out, int out_size, void* d_ws, size_t ws_size,
                              hipStream_t stream) {
  const float* x = (const float*)d_in[0];
  const float* qkv_w = (const float*)d_in[1];
  const float* qkv_b = (const float*)d_in[2];
  const float* proj_w = (const float*)d_in[3];
  const float* proj_b = (const float*)d_in[4];
  const float* rel_pos_h = (const float*)d_in[5];
  const float* rel_pos_w = (const float*)d_in[6];
  float* out = (float*)d_out;

  char* ws = (char*)d_ws;
  u16* x_bf = (u16*)(ws + 0);              // 12,582,912 B (reused as attn out)
  u16* qkvw_bf = (u16*)(ws + 12582912);    //  3,538,944
  u16* projw_bf = (u16*)(ws + 16121856);   //  1,179,648
  u16* qbuf2 = (u16*)(ws + 17301504);      // 25,165,824 (96x1024x128, aug Q)
  u16* kbuf = (u16*)(ws + 42467328);       // 12,582,912 (96x1024x64)
  u16* vtbuf = (u16*)(ws + 55050240);      // 12,582,912
  u16* tbl = (u16*)(ws + 67633152);        //     16,384 -> total 67,649,536
  u16* aobuf = x_bf;                        // alias: x_bf dead after QKV gemm

  prep_kernel<<<2048, 256, 0, stream>>>(x, qkv_w, proj_w, rel_pos_h, rel_pos_w,
                                        x_bf, qkvw_bf, projw_bf, tbl);

  gemm128<<<dim3(18, 64), 512, 0, stream>>>(x_bf, qkvw_bf, qkv_b, qbuf2, kbuf, vtbuf);

  pgemm_kernel<<<384, 256, 0, stream>>>(qbuf2, tbl, qbuf2);

  attn_kernel<<<dim3(96, 8), 256, 0, stream>>>(qbuf2, kbuf, vtbuf, aobuf);

  gemmP<<<dim3(6, 128), 512, 0, stream>>>(aobuf, projw_bf, proj_b, out);
}